// Round 1
// baseline (1198.740 us; speedup 1.0000x reference)
//
#include <hip/hip_runtime.h>
#include <math.h>

#define N_TOK 65536
#define H_DIM 1024

typedef __attribute__((ext_vector_type(8))) short bf16x8;
typedef __attribute__((ext_vector_type(4))) float f32x4;

// ---------------- ws layout (bytes); total need ~277 MB ----------------
static const size_t WS_CNT   = 0;                       // int[4]
static const size_t WS_OFFS  = 64;                      // int[4]
static const size_t WS_PERM  = 128;                     // int[3*N_TOK] = 768KB
static const size_t WS_WT1   = 1ull << 20;              // bf16 [3][1024][1024] = 6MB
static const size_t WS_WT3   = WS_WT1 + 6291456ull;
static const size_t WS_WT2   = WS_WT3 + 6291456ull;
static const size_t WS_XB    = 20ull << 20;             // bf16 [N][H] = 128MB
static const size_t WS_INNER = WS_XB + 134217728ull;    // bf16 [N][H] = 128MB

static __device__ __forceinline__ unsigned short f2bf(float f) {
  union { float f; unsigned int u; } v; v.f = f;
  unsigned int r = v.u + 0x7fffu + ((v.u >> 16) & 1u);
  return (unsigned short)(r >> 16);
}

__global__ void init_kernel(int* cnt) {
  if (threadIdx.x < 4) cnt[threadIdx.x] = 0;
}

// one wave per row: 3 gate logits + gumbel argmax + x->bf16 conversion.
// Block (16 waves) aggregates bucket membership -> 3 atomics per block.
__global__ __launch_bounds__(1024) void gate_kernel(
    const float* __restrict__ x, const float* __restrict__ Wg,
    const float* __restrict__ bg, const float* __restrict__ gu,
    unsigned short* __restrict__ xb, int* __restrict__ cnt,
    int* __restrict__ perm)
{
  __shared__ float wg[3072];
  __shared__ int bexp[16];
  for (int i = threadIdx.x; i < 3072; i += 1024) wg[i] = Wg[i];
  __syncthreads();
  const int wave = threadIdx.x >> 6;
  const int lane = threadIdx.x & 63;
  const int n0 = blockIdx.x * 16;
  const int n = n0 + wave;
  const float4* xrow = (const float4*)(x + (size_t)n * H_DIM);
  unsigned short* xbrow = xb + (size_t)n * H_DIM;
  float s0 = 0.f, s1 = 0.f, s2 = 0.f;
#pragma unroll
  for (int j = 0; j < 4; j++) {
    float4 v = xrow[j * 64 + lane];
    int d0 = (j * 64 + lane) * 4;
    const float* w = &wg[d0 * 3];
    s0 += v.x * w[0] + v.y * w[3] + v.z * w[6] + v.w * w[9];
    s1 += v.x * w[1] + v.y * w[4] + v.z * w[7] + v.w * w[10];
    s2 += v.x * w[2] + v.y * w[5] + v.z * w[8] + v.w * w[11];
    uint2 p;
    p.x = (unsigned)f2bf(v.x) | ((unsigned)f2bf(v.y) << 16);
    p.y = (unsigned)f2bf(v.z) | ((unsigned)f2bf(v.w) << 16);
    ((uint2*)xbrow)[j * 64 + lane] = p;
  }
#pragma unroll
  for (int o = 32; o; o >>= 1) {
    s0 += __shfl_xor(s0, o);
    s1 += __shfl_xor(s1, o);
    s2 += __shfl_xor(s2, o);
  }
  if (lane == 0) {
    const float* u = gu + (size_t)n * 3;
    float l[3] = { s0 + bg[0], s1 + bg[1], s2 + bg[2] };
    int best = 0; float bs = -1e30f;
#pragma unroll
    for (int e = 0; e < 3; e++) {
      float uc = fminf(fmaxf(u[e], 1e-6f), 1.f - 1e-6f);
      float g = -logf(-logf(uc));
      float s = l[e] + g;
      if (s > bs) { bs = s; best = e; }   // strict > == first-max (jnp.argmax)
    }
    bexp[wave] = best;
  }
  __syncthreads();
  if (threadIdx.x == 0) {
    int lc[3] = {0, 0, 0};
    int lpos[16];
    for (int w = 0; w < 16; w++) lpos[w] = lc[bexp[w]]++;
    int lbase[3];
    for (int e = 0; e < 3; e++)
      lbase[e] = lc[e] ? atomicAdd(&cnt[e], lc[e]) : 0;
    for (int w = 0; w < 16; w++) {
      int e = bexp[w];
      perm[e * N_TOK + lbase[e] + lpos[w]] = n0 + w;
    }
  }
}

__global__ void offs_kernel(const int* __restrict__ cnt, int* __restrict__ offs) {
  offs[0] = 0; offs[1] = cnt[0]; offs[2] = cnt[0] + cnt[1]; offs[3] = N_TOK;
}

// W[e][d][h] fp32 -> Wt[e][h][d] bf16 (k-contiguous rows for MFMA B frags)
__global__ __launch_bounds__(256) void wcvt_kernel(
    const float* __restrict__ W1, const float* __restrict__ W3,
    const float* __restrict__ W2,
    unsigned short* __restrict__ wt1, unsigned short* __restrict__ wt3,
    unsigned short* __restrict__ wt2)
{
  const int z = blockIdx.z, e = z / 3, m = z % 3;
  const float* src = (m == 0 ? W1 : (m == 1 ? W3 : W2)) + ((size_t)e << 20);
  unsigned short* dst = (m == 0 ? wt1 : (m == 1 ? wt3 : wt2)) + ((size_t)e << 20);
  __shared__ float t[32][33];
  const int h0 = blockIdx.x * 32, d0 = blockIdx.y * 32;
  const int tx = threadIdx.x, ty = threadIdx.y;
#pragma unroll
  for (int i = 0; i < 4; i++)
    t[ty + i * 8][tx] = src[(size_t)(d0 + ty + i * 8) * H_DIM + h0 + tx];
  __syncthreads();
#pragma unroll
  for (int i = 0; i < 4; i++)
    dst[(size_t)(h0 + ty + i * 8) * H_DIM + d0 + tx] = f2bf(t[tx][ty + i * 8]);
}

// Fused h1/h3 GEMM + bias + activation -> inner (bf16, bucket-compacted).
// 128x128 tile, BK=64, 4 waves, each wave 64x64 (4x4 frags of 16x16x32), dual acc.
__global__ __launch_bounds__(256, 2) void mlp1_kernel(
    const unsigned short* __restrict__ xb,
    const unsigned short* __restrict__ wt1,
    const unsigned short* __restrict__ wt3,
    const float* __restrict__ b1, const float* __restrict__ b3,
    const int* __restrict__ cnt, const int* __restrict__ offs,
    const int* __restrict__ perm,
    unsigned short* __restrict__ inner)
{
  const int e = blockIdx.z;
  const int ce = cnt[e];
  const int m0 = blockIdx.x * 128;
  if (m0 >= ce) return;
  const int n0 = blockIdx.y * 128;

  __shared__ short a_sh[128 * 72];
  __shared__ short p_sh[128 * 72];
  __shared__ short q_sh[128 * 72];

  const int t = threadIdx.x;
  const int br = t >> 3;            // staging row group 0..31
  const int c8 = (t & 7) * 8;       // staging col (bf16 units)
  const unsigned short* w1p = wt1 + ((size_t)e << 20);
  const unsigned short* w3p = wt3 + ((size_t)e << 20);

  size_t arow[4];
#pragma unroll
  for (int j = 0; j < 4; j++) {
    int r = m0 + br + 32 * j;
    int g = perm[e * N_TOK + min(r, ce - 1)];
    arow[j] = (size_t)g * H_DIM;
  }

  const int wave = t >> 6, lane = t & 63;
  const int wm = (wave & 1) * 64, wn = (wave >> 1) * 64;
  const int lr = lane & 15, quad = lane >> 4;

  f32x4 acc1[4][4], acc3[4][4];
#pragma unroll
  for (int a = 0; a < 4; a++)
#pragma unroll
    for (int b = 0; b < 4; b++) {
      acc1[a][b] = (f32x4){0.f, 0.f, 0.f, 0.f};
      acc3[a][b] = (f32x4){0.f, 0.f, 0.f, 0.f};
    }

  for (int k0 = 0; k0 < H_DIM; k0 += 64) {
    __syncthreads();
#pragma unroll
    for (int j = 0; j < 4; j++) {
      int row = br + 32 * j;
      uint4 va = *(const uint4*)(xb + arow[j] + k0 + c8);
      uint4 v1 = *(const uint4*)(w1p + (size_t)(n0 + row) * H_DIM + k0 + c8);
      uint4 v3 = *(const uint4*)(w3p + (size_t)(n0 + row) * H_DIM + k0 + c8);
      *(uint4*)&a_sh[row * 72 + c8] = va;
      *(uint4*)&p_sh[row * 72 + c8] = v1;
      *(uint4*)&q_sh[row * 72 + c8] = v3;
    }
    __syncthreads();
#pragma unroll
    for (int ks = 0; ks < 64; ks += 32) {
      bf16x8 af[4], b1f[4], b3f[4];
#pragma unroll
      for (int i = 0; i < 4; i++)
        af[i] = *(const bf16x8*)&a_sh[(wm + i * 16 + lr) * 72 + ks + quad * 8];
#pragma unroll
      for (int i = 0; i < 4; i++) {
        b1f[i] = *(const bf16x8*)&p_sh[(wn + i * 16 + lr) * 72 + ks + quad * 8];
        b3f[i] = *(const bf16x8*)&q_sh[(wn + i * 16 + lr) * 72 + ks + quad * 8];
      }
#pragma unroll
      for (int i = 0; i < 4; i++)
#pragma unroll
        for (int jn = 0; jn < 4; jn++) {
          acc1[i][jn] = __builtin_amdgcn_mfma_f32_16x16x32_bf16(af[i], b1f[jn], acc1[i][jn], 0, 0, 0);
          acc3[i][jn] = __builtin_amdgcn_mfma_f32_16x16x32_bf16(af[i], b3f[jn], acc3[i][jn], 0, 0, 0);
        }
    }
  }

  const int oe = offs[e];
#pragma unroll
  for (int jn = 0; jn < 4; jn++) {
    int col = n0 + wn + jn * 16 + lr;
    float bb1 = b1[e * H_DIM + col];
    float bb3 = b3[e * H_DIM + col];
#pragma unroll
    for (int i = 0; i < 4; i++) {
#pragma unroll
      for (int r = 0; r < 4; r++) {
        int rl = wm + i * 16 + quad * 4 + r;   // C/D: row=quad*4+reg, col=lane&15
        int rr = m0 + rl;
        if (rr < ce) {
          float h1 = acc1[i][jn][r] + bb1;
          float h3 = acc3[i][jn][r] + bb3;
          float a;
          if (e == 0)      a = h1 / (1.f + expf(-h1));                       // silu
          else if (e == 1) a = 0.5f * h1 * (1.f + erff(h1 * 0.70710678118f)); // exact gelu
          else             a = fmaxf(h1, 0.f);                                // relu
          inner[(size_t)(oe + rr) * H_DIM + col] = f2bf(a * h3);
        }
      }
    }
  }
}

// out = inner @ W2t + b2, scattered back to original row order (fp32)
__global__ __launch_bounds__(256, 2) void mlp2_kernel(
    const unsigned short* __restrict__ inner,
    const unsigned short* __restrict__ wt2,
    const float* __restrict__ b2,
    const int* __restrict__ cnt, const int* __restrict__ offs,
    const int* __restrict__ perm,
    float* __restrict__ out)
{
  const int e = blockIdx.z;
  const int ce = cnt[e];
  const int m0 = blockIdx.x * 128;
  if (m0 >= ce) return;
  const int n0 = blockIdx.y * 128;
  const int oe = offs[e];

  __shared__ short a_sh[128 * 72];
  __shared__ short p_sh[128 * 72];

  const int t = threadIdx.x;
  const int br = t >> 3;
  const int c8 = (t & 7) * 8;
  const unsigned short* w2p = wt2 + ((size_t)e << 20);

  size_t arow[4];
#pragma unroll
  for (int j = 0; j < 4; j++) {
    int r = min(m0 + br + 32 * j, ce - 1);
    arow[j] = (size_t)(oe + r) * H_DIM;
  }

  const int wave = t >> 6, lane = t & 63;
  const int wm = (wave & 1) * 64, wn = (wave >> 1) * 64;
  const int lr = lane & 15, quad = lane >> 4;

  f32x4 acc[4][4];
#pragma unroll
  for (int a = 0; a < 4; a++)
#pragma unroll
    for (int b = 0; b < 4; b++) acc[a][b] = (f32x4){0.f, 0.f, 0.f, 0.f};

  for (int k0 = 0; k0 < H_DIM; k0 += 64) {
    __syncthreads();
#pragma unroll
    for (int j = 0; j < 4; j++) {
      int row = br + 32 * j;
      uint4 va = *(const uint4*)(inner + arow[j] + k0 + c8);
      uint4 vb = *(const uint4*)(w2p + (size_t)(n0 + row) * H_DIM + k0 + c8);
      *(uint4*)&a_sh[row * 72 + c8] = va;
      *(uint4*)&p_sh[row * 72 + c8] = vb;
    }
    __syncthreads();
#pragma unroll
    for (int ks = 0; ks < 64; ks += 32) {
      bf16x8 af[4], bf[4];
#pragma unroll
      for (int i = 0; i < 4; i++)
        af[i] = *(const bf16x8*)&a_sh[(wm + i * 16 + lr) * 72 + ks + quad * 8];
#pragma unroll
      for (int i = 0; i < 4; i++)
        bf[i] = *(const bf16x8*)&p_sh[(wn + i * 16 + lr) * 72 + ks + quad * 8];
#pragma unroll
      for (int i = 0; i < 4; i++)
#pragma unroll
        for (int jn = 0; jn < 4; jn++)
          acc[i][jn] = __builtin_amdgcn_mfma_f32_16x16x32_bf16(af[i], bf[jn], acc[i][jn], 0, 0, 0);
    }
  }

#pragma unroll
  for (int jn = 0; jn < 4; jn++) {
    int col = n0 + wn + jn * 16 + lr;
    float bb2 = b2[e * H_DIM + col];
#pragma unroll
    for (int i = 0; i < 4; i++) {
#pragma unroll
      for (int r = 0; r < 4; r++) {
        int rl = wm + i * 16 + quad * 4 + r;
        int rr = m0 + rl;
        if (rr < ce) {
          int g = perm[e * N_TOK + rr];
          out[(size_t)g * H_DIM + col] = acc[i][jn][r] + bb2;
        }
      }
    }
  }
}

extern "C" void kernel_launch(void* const* d_in, const int* in_sizes, int n_in,
                              void* d_out, int out_size, void* d_ws, size_t ws_size,
                              hipStream_t stream)
{
  const float* x  = (const float*)d_in[0];
  const float* W1 = (const float*)d_in[1];
  const float* b1 = (const float*)d_in[2];
  const float* W2 = (const float*)d_in[3];
  const float* b2 = (const float*)d_in[4];
  const float* W3 = (const float*)d_in[5];
  const float* b3 = (const float*)d_in[6];
  const float* Wg = (const float*)d_in[7];
  const float* bg = (const float*)d_in[8];
  const float* gu = (const float*)d_in[9];
  float* out = (float*)d_out;

  char* ws = (char*)d_ws;
  int* cnt  = (int*)(ws + WS_CNT);
  int* offs = (int*)(ws + WS_OFFS);
  int* perm = (int*)(ws + WS_PERM);
  unsigned short* wt1 = (unsigned short*)(ws + WS_WT1);
  unsigned short* wt3 = (unsigned short*)(ws + WS_WT3);
  unsigned short* wt2 = (unsigned short*)(ws + WS_WT2);
  unsigned short* xb  = (unsigned short*)(ws + WS_XB);
  unsigned short* inner = (unsigned short*)(ws + WS_INNER);

  init_kernel<<<1, 64, 0, stream>>>(cnt);
  gate_kernel<<<N_TOK / 16, 1024, 0, stream>>>(x, Wg, bg, gu, xb, cnt, perm);
  offs_kernel<<<1, 1, 0, stream>>>(cnt, offs);
  wcvt_kernel<<<dim3(32, 32, 9), dim3(32, 8), 0, stream>>>(W1, W3, W2, wt1, wt3, wt2);
  mlp1_kernel<<<dim3(512, 8, 3), 256, 0, stream>>>(xb, wt1, wt3, b1, b3, cnt, offs, perm, inner);
  mlp2_kernel<<<dim3(512, 8, 3), 256, 0, stream>>>(inner, wt2, b2, cnt, offs, perm, out);
}